// Round 1
// baseline (957.228 us; speedup 1.0000x reference)
//
#include <hip/hip_runtime.h>
#include <stdint.h>

// ProposalLayer: top-6000 select -> bbox regression+clip -> greedy NMS -> 2000 proposals
// B=8, N=261888, all float32.

#define BATCH   8
#define NN      261888
#define PRE_NMS 6000
#define NUM_PROP 2000
#define CAND_CAP 8192      // compaction capacity per batch (>= 6000 + histogram slack)
#define EDGE_CAP 16384     // sparse IoU>0.7 edge capacity per batch (expect ~1.5k)
#define NTILE   94         // ceil(6000/64)
#define NPAD    6016       // NTILE*64
#define NW32    188        // suppression bitmask words (u32), 2 per window

// workspace layout (bytes)
#define OFF_HIST1  256
#define OFF_HIST2  (OFF_HIST1 + BATCH*4096*4)
#define OFF_KEY    (OFF_HIST2 + BATCH*4096*4)          // memset covers [0, OFF_KEY)
#define OFF_SORTED (OFF_KEY + BATCH*CAND_CAP*8)
#define OFF_BOXES  (OFF_SORTED + BATCH*PRE_NMS*4)
#define OFF_AREAS  (OFF_BOXES + BATCH*NPAD*16)
#define OFF_EDGES  (OFF_AREAS + BATCH*NPAD*4)
#define WS_NEED    (OFF_EDGES + BATCH*EDGE_CAP*4)      // ~2.47 MB

// state (u32 indices into ws base): [0..7] L1 prefix, [8..15] Krem, [16..23] threshold,
// [24..31] candidate count, [32..39] edge count
__device__ __forceinline__ uint32_t fkey(float s){
  uint32_t b = __float_as_uint(s);
  return (b & 0x80000000u) ? ~b : (b | 0x80000000u);   // order-preserving float->u32
}

// ---- level-1 histogram of top 12 bits of fkey ----
__global__ void k_hist1(const float* __restrict__ probs, char* ws){
  __shared__ uint32_t h[4096];
  int b = blockIdx.y;
  for (int t = threadIdx.x; t < 4096; t += 256) h[t] = 0;
  __syncthreads();
  const float2* p2 = (const float2*)probs + (size_t)b * NN;
  int base = blockIdx.x * 2048;
  for (int k = 0; k < 8; ++k){
    int i = base + k*256 + threadIdx.x;
    if (i < NN) atomicAdd(&h[fkey(p2[i].y) >> 20], 1u);
  }
  __syncthreads();
  uint32_t* gh = (uint32_t*)(ws + OFF_HIST1) + b*4096;
  for (int t = threadIdx.x; t < 4096; t += 256) if (h[t]) atomicAdd(&gh[t], h[t]);
}

// ---- level-2 histogram (bits 19:8) among elements matching L1 prefix ----
__global__ void k_hist2(const float* __restrict__ probs, char* ws){
  __shared__ uint32_t h[4096];
  uint32_t* state = (uint32_t*)ws;
  int b = blockIdx.y;
  uint32_t pref = state[b];
  for (int t = threadIdx.x; t < 4096; t += 256) h[t] = 0;
  __syncthreads();
  const float2* p2 = (const float2*)probs + (size_t)b * NN;
  int base = blockIdx.x * 2048;
  for (int k = 0; k < 8; ++k){
    int i = base + k*256 + threadIdx.x;
    if (i < NN){
      uint32_t u = fkey(p2[i].y);
      if ((u >> 20) == pref) atomicAdd(&h[(u >> 8) & 0xFFFu], 1u);
    }
  }
  __syncthreads();
  uint32_t* gh = (uint32_t*)(ws + OFF_HIST2) + b*4096;
  for (int t = threadIdx.x; t < 4096; t += 256) if (h[t]) atomicAdd(&gh[t], h[t]);
}

// ---- find histogram bin where cumulative-from-top crosses K ----
__global__ void k_resolve(char* ws, int level){
  uint32_t* state = (uint32_t*)ws;
  const uint32_t* gh = (const uint32_t*)(ws + (level == 1 ? OFF_HIST1 : OFF_HIST2)) + blockIdx.x*4096;
  __shared__ uint32_t part[256];
  int b = blockIdx.x, t = threadIdx.x;
  uint32_t s = 0;
  for (int k = 0; k < 16; ++k) s += gh[t*16 + k];
  part[t] = s;
  __syncthreads();
  if (t == 0){
    uint32_t K = (level == 1) ? (uint32_t)PRE_NMS : state[8 + b];
    uint32_t cum = 0; int c = 255;
    for (; c > 0; --c){ if (cum + part[c] >= K) break; cum += part[c]; }
    uint32_t rem = K - cum;
    uint32_t cum2 = 0; int bin = c*16;
    for (int k = 15; k >= 0; --k){
      uint32_t v = gh[c*16 + k];
      if (cum2 + v >= rem){ bin = c*16 + k; rem = rem - cum2; break; }
      cum2 += v;
    }
    if (level == 1){ state[b] = (uint32_t)bin; state[8 + b] = rem; }
    else           { state[16 + b] = (state[b] << 20) | ((uint32_t)bin << 8); }
  }
}

// ---- compact all elements with fkey >= threshold into distinct u64 keys ----
__global__ void k_compact(const float* __restrict__ probs, char* ws){
  uint32_t* state = (uint32_t*)ws;
  uint64_t* keys = (uint64_t*)(ws + OFF_KEY);
  int b = blockIdx.y;
  uint32_t thr = state[16 + b];
  const float2* p2 = (const float2*)probs + (size_t)b * NN;
  int base = blockIdx.x * 2048;
  for (int k = 0; k < 8; ++k){
    int i = base + k*256 + threadIdx.x;
    if (i < NN){
      uint32_t u = fkey(p2[i].y);
      if (u >= thr){
        uint32_t pos = atomicAdd(&state[24 + b], 1u);
        if (pos < CAND_CAP)
          keys[(size_t)b*CAND_CAP + pos] = ((uint64_t)u << 32) | (uint32_t)(~(uint32_t)i);
      }
    }
  }
}

// ---- per-batch bitonic sort (descending) of 8192 u64 keys in LDS; emit top-6000 ids ----
__global__ __launch_bounds__(1024) void k_sort(char* ws){
  __shared__ uint64_t a[CAND_CAP];
  uint32_t* state = (uint32_t*)ws;
  const uint64_t* kb = (const uint64_t*)(ws + OFF_KEY) + (size_t)blockIdx.x * CAND_CAP;
  uint32_t* sorted = (uint32_t*)(ws + OFF_SORTED);
  int b = blockIdx.x, t = threadIdx.x;
  uint32_t cnt = state[24 + b]; if (cnt > CAND_CAP) cnt = CAND_CAP;
  for (int e = t; e < CAND_CAP; e += 1024) a[e] = (e < (int)cnt) ? kb[e] : 0ull;
  __syncthreads();
  for (int k = 2; k <= CAND_CAP; k <<= 1){
    for (int j = k >> 1; j > 0; j >>= 1){
      for (int e = t; e < CAND_CAP; e += 1024){
        int p = e ^ j;
        if (p > e){
          uint64_t x = a[e], y = a[p];
          bool up = (e & k) == 0;
          if (up ? (x < y) : (x > y)){ a[e] = y; a[p] = x; }   // global descending
        }
      }
      __syncthreads();
    }
  }
  for (int kk = t; kk < PRE_NMS; kk += 1024){
    uint32_t id = ~(uint32_t)(a[kk] & 0xFFFFFFFFull);
    if (id >= NN) id = 0;                 // safety (only if <6000 candidates)
    sorted[b*PRE_NMS + kk] = id;
  }
}

// ---- gather deltas/anchors at sorted ids, regress, clip, precompute areas ----
__global__ void k_gather(const float* __restrict__ boff, const float* __restrict__ anc, char* ws){
#pragma clang fp contract(off)
  int t = blockIdx.x*256 + threadIdx.x;
  if (t >= BATCH*PRE_NMS) return;
  int b = t / PRE_NMS, k = t - b*PRE_NMS;
  const uint32_t* sorted = (const uint32_t*)(ws + OFF_SORTED);
  float4* boxes = (float4*)(ws + OFF_BOXES);
  float* areas = (float*)(ws + OFF_AREAS);
  uint32_t id = sorted[b*PRE_NMS + k];
  float4 d4 = ((const float4*)boff)[(size_t)b*NN + id];
  float4 a4 = ((const float4*)anc )[(size_t)b*NN + id];
  float d0 = d4.x*0.1f, d1 = d4.y*0.1f, d2 = d4.z*0.2f, d3 = d4.w*0.2f;
  float h = a4.z - a4.x;
  float w = a4.w - a4.y;
  float cy = a4.x + 0.5f*h + d0*h;
  float cx = a4.y + 0.5f*w + d1*w;
  float h2 = h * expf(d2);
  float w2 = w * expf(d3);
  float y1 = cy - 0.5f*h2, x1 = cx - 0.5f*w2;
  float y2 = cy + 0.5f*h2, x2 = cx + 0.5f*w2;
  y1 = fminf(fmaxf(y1, 0.f), 1.f);
  x1 = fminf(fmaxf(x1, 0.f), 1.f);
  y2 = fminf(fmaxf(y2, 0.f), 1.f);
  x2 = fminf(fmaxf(x2, 0.f), 1.f);
  boxes[(size_t)b*NPAD + k] = make_float4(y1, x1, y2, x2);
  areas[(size_t)b*NPAD + k] = (y2 - y1) * (x2 - x1);
}

// ---- sparse edge build: all pairs i<j with IoU > 0.7 (tiled 64x64, upper triangle) ----
__global__ __launch_bounds__(64) void k_edges(char* ws){
#pragma clang fp contract(off)
  uint32_t* state = (uint32_t*)ws;
  const float4* boxes = (const float4*)(ws + OFF_BOXES);
  const float* areas = (const float*)(ws + OFF_AREAS);
  uint32_t* edges = (uint32_t*)(ws + OFF_EDGES);
  int b = blockIdx.y, t = threadIdx.x;
  int p = blockIdx.x, ti = 0;
  while (p >= NTILE - ti){ p -= NTILE - ti; ++ti; }   // triangular decode
  int tj = ti + p;
  __shared__ float4 cb[64];
  __shared__ float  ca[64];
  int j0 = tj*64 + t;
  cb[t] = boxes[(size_t)b*NPAD + j0];
  ca[t] = areas[(size_t)b*NPAD + j0];
  __syncthreads();
  int i = ti*64 + t;
  if (i >= PRE_NMS) return;
  float4 bi = boxes[(size_t)b*NPAD + i];
  float ai = areas[(size_t)b*NPAD + i];
  for (int jj = 0; jj < 64; ++jj){
    int j = tj*64 + jj;
    if (j <= i || j >= PRE_NMS) continue;
    float4 bj = cb[jj];
    float yy1 = fmaxf(bi.x, bj.x);
    float xx1 = fmaxf(bi.y, bj.y);
    float yy2 = fminf(bi.z, bj.z);
    float xx2 = fminf(bi.w, bj.w);
    float ih = fmaxf(yy2 - yy1, 0.f);
    float iw = fmaxf(xx2 - xx1, 0.f);
    float inter = ih * iw;
    float uni = ai + ca[jj] - inter + 1e-9f;   // ((ai+aj)-inter)+1e-9, matches ref order
    float iou = inter / uni;
    if (iou > 0.7f){
      uint32_t pos = atomicAdd(&state[32 + b], 1u);
      if (pos < EDGE_CAP) edges[(size_t)b*EDGE_CAP + pos] = (uint32_t)i | ((uint32_t)j << 13);
    }
  }
}

// ---- greedy NMS sweep: CSR-bucket edges in LDS, then wave-synchronous window scan ----
__global__ __launch_bounds__(256) void k_scan(char* ws, float* __restrict__ out){
  __shared__ uint32_t deg[NPAD + 1];
  __shared__ uint32_t offs[NPAD + 1];
  __shared__ uint16_t ebuf[EDGE_CAP];
  __shared__ uint32_t suppr[NW32];
  __shared__ uint64_t hasS[NTILE];
  __shared__ uint32_t part[256];
  uint32_t* state = (uint32_t*)ws;
  const uint32_t* eb = (const uint32_t*)(ws + OFF_EDGES) + (size_t)blockIdx.x * EDGE_CAP;
  const float4* boxes = (const float4*)(ws + OFF_BOXES);
  int b = blockIdx.x, t = threadIdx.x;

  for (int i = t; i <= NPAD; i += 256) deg[i] = 0;
  for (int i = t; i < NW32; i += 256) suppr[i] = 0;
  __syncthreads();
  uint32_t E = state[32 + b]; if (E > EDGE_CAP) E = EDGE_CAP;
  for (uint32_t e = t; e < E; e += 256) atomicAdd(&deg[eb[e] & 0x1FFFu], 1u);
  __syncthreads();
  const int CH = 24;                                    // 24*256 >= NPAD+1
  uint32_t s = 0;
  for (int k = 0; k < CH; ++k){ int i = t*CH + k; if (i <= NPAD) s += deg[i]; }
  part[t] = s;
  __syncthreads();
  if (t == 0){ uint32_t run = 0; for (int c = 0; c < 256; ++c){ uint32_t v = part[c]; part[c] = run; run += v; } }
  __syncthreads();
  uint32_t run = part[t];
  for (int k = 0; k < CH; ++k){ int i = t*CH + k; if (i <= NPAD){ offs[i] = run; run += deg[i]; } }
  __syncthreads();
  for (int w = t; w < NTILE; w += 256){
    uint64_t m = 0;
    for (int l = 0; l < 64; ++l){
      int j = w*64 + l;
      if (j < PRE_NMS && deg[j] > 0) m |= (1ull << l);
    }
    hasS[w] = m;
  }
  __syncthreads();
  for (int i = t; i <= NPAD; i += 256) deg[i] = 0;      // reuse as scatter cursor
  __syncthreads();
  for (uint32_t e = t; e < E; e += 256){
    uint32_t ed = eb[e];
    uint32_t ii = ed & 0x1FFFu, jj = ed >> 13;
    uint32_t slot = atomicAdd(&deg[ii], 1u);
    ebuf[offs[ii] + slot] = (uint16_t)jj;
  }
  __syncthreads();
  if (t >= 64) return;                                  // serial phase: wave 0 only
  int lane = t;
  uint32_t nsel = 0;
  for (int w = 0; w < NTILE && nsel < NUM_PROP; ++w){
    int base = w*64;
    int jme = base + lane;
    float4 mybox = boxes[(size_t)b*NPAD + jme];
    uint32_t o0me = offs[jme];
    uint32_t o1me = offs[jme + 1];
    uint64_t sup = (uint64_t)suppr[2*w] | ((uint64_t)suppr[2*w + 1] << 32);
    uint64_t hs = hasS[w];
    uint64_t live = ~sup;
    int valid = PRE_NMS - base;
    if (valid < 64) live &= ((1ull << valid) - 1ull);
    uint64_t m = live;
    if ((hs & m) == 0ull){
      // fast path: nothing live here can suppress anything -> take in order
      uint32_t cnt = __popcll(m);
      uint32_t remn = NUM_PROP - nsel;
      uint32_t take = cnt < remn ? cnt : remn;
      if (m & (1ull << lane)){
        uint32_t r = __popcll(m & ((1ull << lane) - 1ull));
        if (r < take) ((float4*)out)[(size_t)b*NUM_PROP + nsel + r] = mybox;
      }
      nsel += take;
    } else {
      while (m && nsel < NUM_PROP){
        int f = __ffsll((unsigned long long)m) - 1;
        m &= m - 1;
        if (lane == f) ((float4*)out)[(size_t)b*NUM_PROP + nsel] = mybox;
        nsel++;
        if (hs & (1ull << f)){
          int j = base + f;
          uint32_t o0 = __shfl(o0me, f);
          uint32_t o1 = __shfl(o1me, f);
          uint32_t len = o1 - o0;
          uint32_t clo = 0, chi = 0;
          for (uint32_t s0 = 0; s0 < len; s0 += 64){
            uint32_t idx = s0 + (uint32_t)lane;
            int sj = (idx < len) ? (int)ebuf[o0 + idx] : -1;
            uint32_t wlo = 0, whi = 0;
            if (sj >= 0){
              if ((sj >> 6) == w){
                int l2 = sj & 63;
                if (l2 < 32) wlo = 1u << l2; else whi = 1u << (l2 - 32);
              } else {
                atomicOr(&suppr[sj >> 5], 1u << (sj & 31));  // future windows
              }
            }
            for (int d = 32; d >= 1; d >>= 1){ wlo |= __shfl_xor(wlo, d); whi |= __shfl_xor(whi, d); }
            clo |= wlo; chi |= whi;
          }
          m &= ~((uint64_t)clo | ((uint64_t)chi << 32));
          (void)j;
        }
      }
    }
  }
  for (uint32_t r = nsel + (uint32_t)lane; r < NUM_PROP; r += 64)
    ((float4*)out)[(size_t)b*NUM_PROP + r] = make_float4(0.f, 0.f, 0.f, 0.f);
}

extern "C" void kernel_launch(void* const* d_in, const int* in_sizes, int n_in,
                              void* d_out, int out_size, void* d_ws, size_t ws_size,
                              hipStream_t stream){
  const float* probs = (const float*)d_in[0];
  const float* boff  = (const float*)d_in[1];
  const float* anc   = (const float*)d_in[2];
  char* ws = (char*)d_ws;
  float* out = (float*)d_out;

  hipMemsetAsync(ws, 0, OFF_KEY, stream);  // zero state + both histograms
  k_hist1  <<<dim3(128, BATCH), 256, 0, stream>>>(probs, ws);
  k_resolve<<<BATCH, 256, 0, stream>>>(ws, 1);
  k_hist2  <<<dim3(128, BATCH), 256, 0, stream>>>(probs, ws);
  k_resolve<<<BATCH, 256, 0, stream>>>(ws, 2);
  k_compact<<<dim3(128, BATCH), 256, 0, stream>>>(probs, ws);
  k_sort   <<<BATCH, 1024, 0, stream>>>(ws);
  k_gather <<<(BATCH*PRE_NMS + 255)/256, 256, 0, stream>>>(boff, anc, ws);
  k_edges  <<<dim3(NTILE*(NTILE+1)/2, BATCH), 64, 0, stream>>>(ws);
  k_scan   <<<BATCH, 256, 0, stream>>>(ws, out);
}

// Round 2
// 638.262 us; speedup vs baseline: 1.4997x; 1.4997x over previous
//
#include <hip/hip_runtime.h>
#include <stdint.h>

// ProposalLayer: top-6000 select -> bbox regression+clip -> greedy NMS -> 2000 proposals
// B=8, N=261888, all float32.

#define BATCH   8
#define NN      261888
#define PRE_NMS 6000
#define NUM_PROP 2000
#define CAND_CAP 8192      // compaction capacity per batch (>= 6000 + histogram slack)
#define EDGE_CAP 16384     // sparse IoU>0.7 edge capacity per batch
#define NTILE   94         // ceil(6000/64)
#define NPAD    6016       // NTILE*64
#define NW32    188        // suppression bitmask words (u32), 2 per window

// workspace layout (bytes)
#define OFF_HIST1  256
#define OFF_HIST2  (OFF_HIST1 + BATCH*4096*4)
#define OFF_KEY    (OFF_HIST2 + BATCH*4096*4)          // memset covers [0, OFF_KEY)
#define OFF_SORTED (OFF_KEY + BATCH*CAND_CAP*8)
#define OFF_BOXES  (OFF_SORTED + BATCH*PRE_NMS*4)
#define OFF_AREAS  (OFF_BOXES + BATCH*NPAD*16)
#define OFF_EDGES  (OFF_AREAS + BATCH*NPAD*4)
#define WS_NEED    (OFF_EDGES + BATCH*EDGE_CAP*4)      // ~2.47 MB

// state (u32 indices into ws base): [0..7] L1 prefix, [8..15] Krem, [16..23] threshold,
// [24..31] candidate count, [32..39] edge count
__device__ __forceinline__ uint32_t fkey(float s){
  uint32_t b = __float_as_uint(s);
  return (b & 0x80000000u) ? ~b : (b | 0x80000000u);   // order-preserving float->u32
}

__device__ __forceinline__ uint64_t shfl64(uint64_t v, int src){
  uint32_t lo = __shfl((uint32_t)(v & 0xFFFFFFFFull), src, 64);
  uint32_t hi = __shfl((uint32_t)(v >> 32), src, 64);
  return (uint64_t)lo | ((uint64_t)hi << 32);
}

// ---- level-1 histogram of top 12 bits of fkey ----
__global__ void k_hist1(const float* __restrict__ probs, char* ws){
  __shared__ uint32_t h[4096];
  int b = blockIdx.y;
  for (int t = threadIdx.x; t < 4096; t += 256) h[t] = 0;
  __syncthreads();
  const float2* p2 = (const float2*)probs + (size_t)b * NN;
  int base = blockIdx.x * 2048;
  for (int k = 0; k < 8; ++k){
    int i = base + k*256 + threadIdx.x;
    if (i < NN) atomicAdd(&h[fkey(p2[i].y) >> 20], 1u);
  }
  __syncthreads();
  uint32_t* gh = (uint32_t*)(ws + OFF_HIST1) + b*4096;
  for (int t = threadIdx.x; t < 4096; t += 256) if (h[t]) atomicAdd(&gh[t], h[t]);
}

// ---- level-2 histogram (bits 19:8) among elements matching L1 prefix ----
__global__ void k_hist2(const float* __restrict__ probs, char* ws){
  __shared__ uint32_t h[4096];
  uint32_t* state = (uint32_t*)ws;
  int b = blockIdx.y;
  uint32_t pref = state[b];
  for (int t = threadIdx.x; t < 4096; t += 256) h[t] = 0;
  __syncthreads();
  const float2* p2 = (const float2*)probs + (size_t)b * NN;
  int base = blockIdx.x * 2048;
  for (int k = 0; k < 8; ++k){
    int i = base + k*256 + threadIdx.x;
    if (i < NN){
      uint32_t u = fkey(p2[i].y);
      if ((u >> 20) == pref) atomicAdd(&h[(u >> 8) & 0xFFFu], 1u);
    }
  }
  __syncthreads();
  uint32_t* gh = (uint32_t*)(ws + OFF_HIST2) + b*4096;
  for (int t = threadIdx.x; t < 4096; t += 256) if (h[t]) atomicAdd(&gh[t], h[t]);
}

// ---- find histogram bin where cumulative-from-top crosses K ----
__global__ void k_resolve(char* ws, int level){
  uint32_t* state = (uint32_t*)ws;
  const uint32_t* gh = (const uint32_t*)(ws + (level == 1 ? OFF_HIST1 : OFF_HIST2)) + blockIdx.x*4096;
  __shared__ uint32_t part[256];
  int b = blockIdx.x, t = threadIdx.x;
  uint32_t s = 0;
  for (int k = 0; k < 16; ++k) s += gh[t*16 + k];
  part[t] = s;
  __syncthreads();
  if (t == 0){
    uint32_t K = (level == 1) ? (uint32_t)PRE_NMS : state[8 + b];
    uint32_t cum = 0; int c = 255;
    for (; c > 0; --c){ if (cum + part[c] >= K) break; cum += part[c]; }
    uint32_t rem = K - cum;
    uint32_t cum2 = 0; int bin = c*16;
    for (int k = 15; k >= 0; --k){
      uint32_t v = gh[c*16 + k];
      if (cum2 + v >= rem){ bin = c*16 + k; rem = rem - cum2; break; }
      cum2 += v;
    }
    if (level == 1){ state[b] = (uint32_t)bin; state[8 + b] = rem; }
    else           { state[16 + b] = (state[b] << 20) | ((uint32_t)bin << 8); }
  }
}

// ---- compact all elements with fkey >= threshold into distinct u64 keys ----
__global__ void k_compact(const float* __restrict__ probs, char* ws){
  uint32_t* state = (uint32_t*)ws;
  uint64_t* keys = (uint64_t*)(ws + OFF_KEY);
  int b = blockIdx.y;
  uint32_t thr = state[16 + b];
  const float2* p2 = (const float2*)probs + (size_t)b * NN;
  int base = blockIdx.x * 2048;
  for (int k = 0; k < 8; ++k){
    int i = base + k*256 + threadIdx.x;
    if (i < NN){
      uint32_t u = fkey(p2[i].y);
      if (u >= thr){
        uint32_t pos = atomicAdd(&state[24 + b], 1u);
        if (pos < CAND_CAP)
          keys[(size_t)b*CAND_CAP + pos] = ((uint64_t)u << 32) | (uint32_t)(~(uint32_t)i);
      }
    }
  }
}

// ---- per-batch bitonic sort (descending) of 8192 u64 keys in LDS; emit top-6000 ids ----
__global__ __launch_bounds__(1024) void k_sort(char* ws){
  __shared__ uint64_t a[CAND_CAP];
  uint32_t* state = (uint32_t*)ws;
  const uint64_t* kb = (const uint64_t*)(ws + OFF_KEY) + (size_t)blockIdx.x * CAND_CAP;
  uint32_t* sorted = (uint32_t*)(ws + OFF_SORTED);
  int b = blockIdx.x, t = threadIdx.x;
  uint32_t cnt = state[24 + b]; if (cnt > CAND_CAP) cnt = CAND_CAP;
  for (int e = t; e < CAND_CAP; e += 1024) a[e] = (e < (int)cnt) ? kb[e] : 0ull;
  __syncthreads();
  for (int k = 2; k <= CAND_CAP; k <<= 1){
    for (int j = k >> 1; j > 0; j >>= 1){
      for (int e = t; e < CAND_CAP; e += 1024){
        int p = e ^ j;
        if (p > e){
          uint64_t x = a[e], y = a[p];
          bool up = (e & k) == 0;
          if (up ? (x < y) : (x > y)){ a[e] = y; a[p] = x; }   // global descending
        }
      }
      __syncthreads();
    }
  }
  for (int kk = t; kk < PRE_NMS; kk += 1024){
    uint32_t id = ~(uint32_t)(a[kk] & 0xFFFFFFFFull);
    if (id >= NN) id = 0;                 // safety (only if <6000 candidates)
    sorted[b*PRE_NMS + kk] = id;
  }
}

// ---- gather deltas/anchors at sorted ids, regress, clip, precompute areas ----
__global__ void k_gather(const float* __restrict__ boff, const float* __restrict__ anc, char* ws){
#pragma clang fp contract(off)
  int t = blockIdx.x*256 + threadIdx.x;
  if (t >= BATCH*PRE_NMS) return;
  int b = t / PRE_NMS, k = t - b*PRE_NMS;
  const uint32_t* sorted = (const uint32_t*)(ws + OFF_SORTED);
  float4* boxes = (float4*)(ws + OFF_BOXES);
  float* areas = (float*)(ws + OFF_AREAS);
  uint32_t id = sorted[b*PRE_NMS + k];
  float4 d4 = ((const float4*)boff)[(size_t)b*NN + id];
  float4 a4 = ((const float4*)anc )[(size_t)b*NN + id];
  float d0 = d4.x*0.1f, d1 = d4.y*0.1f, d2 = d4.z*0.2f, d3 = d4.w*0.2f;
  float h = a4.z - a4.x;
  float w = a4.w - a4.y;
  float cy = a4.x + 0.5f*h + d0*h;
  float cx = a4.y + 0.5f*w + d1*w;
  float h2 = h * expf(d2);
  float w2 = w * expf(d3);
  float y1 = cy - 0.5f*h2, x1 = cx - 0.5f*w2;
  float y2 = cy + 0.5f*h2, x2 = cx + 0.5f*w2;
  y1 = fminf(fmaxf(y1, 0.f), 1.f);
  x1 = fminf(fmaxf(x1, 0.f), 1.f);
  y2 = fminf(fmaxf(y2, 0.f), 1.f);
  x2 = fminf(fmaxf(x2, 0.f), 1.f);
  boxes[(size_t)b*NPAD + k] = make_float4(y1, x1, y2, x2);
  areas[(size_t)b*NPAD + k] = (y2 - y1) * (x2 - x1);
}

// ---- sparse edge build: all pairs i<j with IoU > 0.7 (tiled 64x64, upper triangle) ----
__global__ __launch_bounds__(64) void k_edges(char* ws){
#pragma clang fp contract(off)
  uint32_t* state = (uint32_t*)ws;
  const float4* boxes = (const float4*)(ws + OFF_BOXES);
  const float* areas = (const float*)(ws + OFF_AREAS);
  uint32_t* edges = (uint32_t*)(ws + OFF_EDGES);
  int b = blockIdx.y, t = threadIdx.x;
  int p = blockIdx.x, ti = 0;
  while (p >= NTILE - ti){ p -= NTILE - ti; ++ti; }   // triangular decode
  int tj = ti + p;
  __shared__ float4 cb[64];
  __shared__ float  ca[64];
  int j0 = tj*64 + t;
  cb[t] = boxes[(size_t)b*NPAD + j0];
  ca[t] = areas[(size_t)b*NPAD + j0];
  __syncthreads();
  int i = ti*64 + t;
  if (i >= PRE_NMS) return;
  float4 bi = boxes[(size_t)b*NPAD + i];
  float ai = areas[(size_t)b*NPAD + i];
  for (int jj = 0; jj < 64; ++jj){
    int j = tj*64 + jj;
    if (j <= i || j >= PRE_NMS) continue;
    float4 bj = cb[jj];
    float yy1 = fmaxf(bi.x, bj.x);
    float xx1 = fmaxf(bi.y, bj.y);
    float yy2 = fminf(bi.z, bj.z);
    float xx2 = fminf(bi.w, bj.w);
    float ih = fmaxf(yy2 - yy1, 0.f);
    float iw = fmaxf(xx2 - xx1, 0.f);
    float inter = ih * iw;
    float uni = ai + ca[jj] - inter + 1e-9f;   // ((ai+aj)-inter)+1e-9, matches ref order
    float iou = inter / uni;
    if (iou > 0.7f){
      uint32_t pos = atomicAdd(&state[32 + b], 1u);
      if (pos < EDGE_CAP) edges[(size_t)b*EDGE_CAP + pos] = (uint32_t)i | ((uint32_t)j << 13);
    }
  }
}

// ---- greedy NMS sweep ----
// CSR-bucket edges in LDS, then per 64-box window: apply accumulated suppressions,
// build in-window adjacency from sparse edges; if none among live boxes (common),
// select all live in order; else serial with 1 shuffle/step. Cross-window
// suppressions of SELECTED boxes are scattered lane-parallel once per window.
__global__ __launch_bounds__(256) void k_scan(char* ws, float* __restrict__ out){
  __shared__ uint32_t deg[NPAD + 1];
  __shared__ uint32_t offs[NPAD + 1];
  __shared__ uint32_t ebuf[EDGE_CAP];      // (i&63)<<16 | j
  __shared__ uint32_t suppr[NW32];
  __shared__ uint32_t part[256];
  __shared__ uint32_t adjlo[64];
  __shared__ uint32_t adjhi[64];
  uint32_t* state = (uint32_t*)ws;
  const uint32_t* eb = (const uint32_t*)(ws + OFF_EDGES) + (size_t)blockIdx.x * EDGE_CAP;
  const float4* boxes = (const float4*)(ws + OFF_BOXES);
  int b = blockIdx.x, t = threadIdx.x;

  for (int i = t; i <= NPAD; i += 256) deg[i] = 0;
  for (int i = t; i < NW32; i += 256) suppr[i] = 0;
  __syncthreads();
  uint32_t E = state[32 + b]; if (E > EDGE_CAP) E = EDGE_CAP;
  for (uint32_t e = t; e < E; e += 256) atomicAdd(&deg[eb[e] & 0x1FFFu], 1u);
  __syncthreads();
  const int CH = 24;                                    // 24*256 >= NPAD+1
  uint32_t s = 0;
  for (int k = 0; k < CH; ++k){ int i = t*CH + k; if (i <= NPAD) s += deg[i]; }
  part[t] = s;
  __syncthreads();
  if (t == 0){ uint32_t run = 0; for (int c = 0; c < 256; ++c){ uint32_t v = part[c]; part[c] = run; run += v; } }
  __syncthreads();
  uint32_t run = part[t];
  for (int k = 0; k < CH; ++k){ int i = t*CH + k; if (i <= NPAD){ offs[i] = run; run += deg[i]; } }
  __syncthreads();
  for (int i = t; i <= NPAD; i += 256) deg[i] = 0;      // reuse as scatter cursor
  __syncthreads();
  for (uint32_t e = t; e < E; e += 256){
    uint32_t ed = eb[e];
    uint32_t ii = ed & 0x1FFFu, jj = ed >> 13;
    uint32_t slot = atomicAdd(&deg[ii], 1u);
    ebuf[offs[ii] + slot] = ((ii & 63u) << 16) | jj;
  }
  __syncthreads();
  if (t >= 64) return;                                  // serial phase: wave 0 only
  int lane = t;
  uint32_t nsel = 0;
  for (int w = 0; w < NTILE && nsel < NUM_PROP; ++w){
    int base = w*64;
    adjlo[lane] = 0; adjhi[lane] = 0;
    float4 mybox = boxes[(size_t)b*NPAD + base + lane];
    uint64_t sup = (uint64_t)suppr[2*w] | ((uint64_t)suppr[2*w + 1] << 32);
    uint64_t live = ~sup;
    int valid = PRE_NMS - base;
    if (valid < 64) live &= ((1ull << valid) - 1ull);
    uint32_t r0 = offs[base], r1 = offs[base + 64];
    // pass 1: build in-window adjacency among live-at-entry sources
    bool anyIn = false;
    for (uint32_t idx = r0 + (uint32_t)lane; idx < r1; idx += 64){
      uint32_t e = ebuf[idx];
      uint32_t il = e >> 16, j = e & 0xFFFFu;
      if (((live >> il) & 1ull) && j < (uint32_t)(base + 64)){
        uint32_t l2 = j - (uint32_t)base;
        if (l2 < 32) atomicOr(&adjlo[il], 1u << l2);
        else         atomicOr(&adjhi[il], 1u << (l2 - 32));
        anyIn = true;
      }
    }
    anyIn = __any((int)anyIn);
    uint64_t sel;
    if (!anyIn){
      uint32_t cnt = __popcll(live);
      uint32_t remn = NUM_PROP - nsel;
      uint32_t take = cnt < remn ? cnt : remn;
      if (live & (1ull << lane)){
        uint32_t r = __popcll(live & ((1ull << lane) - 1ull));
        if (r < take) ((float4*)out)[(size_t)b*NUM_PROP + nsel + r] = mybox;
      }
      nsel += take;
      sel = live;               // take<cnt only when hitting 2000 -> loop exits
    } else {
      uint64_t row = (uint64_t)adjlo[lane] | ((uint64_t)adjhi[lane] << 32);
      uint64_t m = live;
      sel = 0;
      while (m && nsel < NUM_PROP){
        int f = __ffsll((unsigned long long)m) - 1;
        m &= m - 1;
        sel |= 1ull << f;
        if (lane == f) ((float4*)out)[(size_t)b*NUM_PROP + nsel] = mybox;
        nsel++;
        m &= ~shfl64(row, f);
      }
    }
    if (nsel >= NUM_PROP) break;
    // pass 2: scatter cross-window suppressions of selected sources
    for (uint32_t idx = r0 + (uint32_t)lane; idx < r1; idx += 64){
      uint32_t e = ebuf[idx];
      uint32_t il = e >> 16, j = e & 0xFFFFu;
      if (((sel >> il) & 1ull) && j >= (uint32_t)(base + 64))
        atomicOr(&suppr[j >> 5], 1u << (j & 31));
    }
  }
  for (uint32_t r = nsel + (uint32_t)lane; r < NUM_PROP; r += 64)
    ((float4*)out)[(size_t)b*NUM_PROP + r] = make_float4(0.f, 0.f, 0.f, 0.f);
}

extern "C" void kernel_launch(void* const* d_in, const int* in_sizes, int n_in,
                              void* d_out, int out_size, void* d_ws, size_t ws_size,
                              hipStream_t stream){
  const float* probs = (const float*)d_in[0];
  const float* boff  = (const float*)d_in[1];
  const float* anc   = (const float*)d_in[2];
  char* ws = (char*)d_ws;
  float* out = (float*)d_out;

  hipMemsetAsync(ws, 0, OFF_KEY, stream);  // zero state + both histograms
  k_hist1  <<<dim3(128, BATCH), 256, 0, stream>>>(probs, ws);
  k_resolve<<<BATCH, 256, 0, stream>>>(ws, 1);
  k_hist2  <<<dim3(128, BATCH), 256, 0, stream>>>(probs, ws);
  k_resolve<<<BATCH, 256, 0, stream>>>(ws, 2);
  k_compact<<<dim3(128, BATCH), 256, 0, stream>>>(probs, ws);
  k_sort   <<<BATCH, 1024, 0, stream>>>(ws);
  k_gather <<<(BATCH*PRE_NMS + 255)/256, 256, 0, stream>>>(boff, anc, ws);
  k_edges  <<<dim3(NTILE*(NTILE+1)/2, BATCH), 64, 0, stream>>>(ws);
  k_scan   <<<BATCH, 256, 0, stream>>>(ws, out);
}

// Round 4
// 387.519 us; speedup vs baseline: 2.4701x; 1.6470x over previous
//
#include <hip/hip_runtime.h>
#include <stdint.h>

// ProposalLayer: top-6000 select -> bbox regression+clip -> greedy NMS -> 2000 proposals
// B=8, N=261888, all float32.

#define BATCH   8
#define NN      261888
#define PRE_NMS 6000
#define NUM_PROP 2000
#define CAND_CAP 8192
#define EDGE_CAP 16384
#define NTILE   94         // ceil(6000/64)
#define NPAD    6016       // NTILE*64
#define NW32    188

// workspace layout (bytes)
#define OFF_HIST1  4096
#define OFF_HIST2  (OFF_HIST1 + BATCH*4096*4)
#define OFF_KEY    (OFF_HIST2 + BATCH*4096*4)          // memset covers [0, OFF_KEY)
#define OFF_SORTED (OFF_KEY + BATCH*CAND_CAP*8)
#define OFF_BOXES  (OFF_SORTED + BATCH*PRE_NMS*4)
#define OFF_AREAS  (OFF_BOXES + BATCH*NPAD*16)
#define OFF_EDGES  (OFF_AREAS + BATCH*NPAD*4)
#define WS_NEED    (OFF_EDGES + BATCH*EDGE_CAP*4)      // ~2.47 MB (same as passing R2)

// state u32 indices: [b]=L1 bin, [8+b]=Krem, [16+b]=threshold.
// Counters spread 128B (32 u32) apart: one cache line per batch, not 8 per line.
#define CNT_KEY(b)   (64  + (b)*32)
#define CNT_EDGE(b)  (320 + (b)*32)

__device__ __forceinline__ uint32_t fkey(float s){
  uint32_t b = __float_as_uint(s);
  return (b & 0x80000000u) ? ~b : (b | 0x80000000u);   // order-preserving float->u32
}

__device__ __forceinline__ uint64_t shfl64(uint64_t v, int src){
  uint32_t lo = __shfl((uint32_t)(v & 0xFFFFFFFFull), src, 64);
  uint32_t hi = __shfl((uint32_t)(v >> 32), src, 64);
  return (uint64_t)lo | ((uint64_t)hi << 32);
}

// wave-aggregated counter reservation: one atomic per wave instead of per lane.
// Returns this lane's slot (valid only when pred).
__device__ __forceinline__ uint32_t wave_reserve(bool pred, uint32_t* ctr){
  uint64_t m = __ballot((int)pred);
  if (!m) return 0xFFFFFFFFu;
  int lane = (int)(threadIdx.x & 63u);
  int leader = __ffsll((unsigned long long)m) - 1;
  uint32_t base = 0;
  if (lane == leader) base = atomicAdd(ctr, (uint32_t)__popcll(m));
  base = __shfl(base, leader, 64);
  return base + (uint32_t)__popcll(m & ((1ull << lane) - 1ull));
}

// ---- level-1 histogram of top 12 bits of fkey ----
__global__ void k_hist1(const float* __restrict__ probs, char* ws){
  __shared__ uint32_t h[4096];
  int b = blockIdx.y;
  for (int t = threadIdx.x; t < 4096; t += 256) h[t] = 0;
  __syncthreads();
  const float2* p2 = (const float2*)probs + (size_t)b * NN;
  int base = blockIdx.x * 2048;
  for (int k = 0; k < 8; ++k){
    int i = base + k*256 + threadIdx.x;
    if (i < NN) atomicAdd(&h[fkey(p2[i].y) >> 20], 1u);
  }
  __syncthreads();
  uint32_t* gh = (uint32_t*)(ws + OFF_HIST1) + b*4096;
  for (int t = threadIdx.x; t < 4096; t += 256) if (h[t]) atomicAdd(&gh[t], h[t]);
}

// ---- level-2 histogram (bits 19:8) among elements matching L1 prefix ----
__global__ void k_hist2(const float* __restrict__ probs, char* ws){
  __shared__ uint32_t h[4096];
  uint32_t* state = (uint32_t*)ws;
  int b = blockIdx.y;
  uint32_t pref = state[b];
  for (int t = threadIdx.x; t < 4096; t += 256) h[t] = 0;
  __syncthreads();
  const float2* p2 = (const float2*)probs + (size_t)b * NN;
  int base = blockIdx.x * 2048;
  for (int k = 0; k < 8; ++k){
    int i = base + k*256 + threadIdx.x;
    if (i < NN){
      uint32_t u = fkey(p2[i].y);
      if ((u >> 20) == pref) atomicAdd(&h[(u >> 8) & 0xFFFu], 1u);
    }
  }
  __syncthreads();
  uint32_t* gh = (uint32_t*)(ws + OFF_HIST2) + b*4096;
  for (int t = threadIdx.x; t < 4096; t += 256) if (h[t]) atomicAdd(&gh[t], h[t]);
}

// ---- find histogram bin where cumulative-from-top crosses K ----
__global__ void k_resolve(char* ws, int level){
  uint32_t* state = (uint32_t*)ws;
  const uint32_t* gh = (const uint32_t*)(ws + (level == 1 ? OFF_HIST1 : OFF_HIST2)) + blockIdx.x*4096;
  __shared__ uint32_t part[256];
  int b = blockIdx.x, t = threadIdx.x;
  uint32_t s = 0;
  for (int k = 0; k < 16; ++k) s += gh[t*16 + k];
  part[t] = s;
  __syncthreads();
  if (t == 0){
    uint32_t K = (level == 1) ? (uint32_t)PRE_NMS : state[8 + b];
    uint32_t cum = 0; int c = 255;
    for (; c > 0; --c){ if (cum + part[c] >= K) break; cum += part[c]; }
    uint32_t rem = K - cum;
    uint32_t cum2 = 0; int bin = c*16;
    for (int k = 15; k >= 0; --k){
      uint32_t v = gh[c*16 + k];
      if (cum2 + v >= rem){ bin = c*16 + k; rem = rem - cum2; break; }
      cum2 += v;
    }
    if (level == 1){ state[b] = (uint32_t)bin; state[8 + b] = rem; }
    else           { state[16 + b] = (state[b] << 20) | ((uint32_t)bin << 8); }
  }
}

// ---- compact all elements with fkey >= threshold into distinct u64 keys ----
__global__ void k_compact(const float* __restrict__ probs, char* ws){
  uint32_t* state = (uint32_t*)ws;
  uint64_t* keys = (uint64_t*)(ws + OFF_KEY);
  int b = blockIdx.y;
  uint32_t thr = state[16 + b];
  const float2* p2 = (const float2*)probs + (size_t)b * NN;
  int base = blockIdx.x * 2048;
  for (int k = 0; k < 8; ++k){
    int i = base + k*256 + threadIdx.x;
    bool hit = false; uint32_t u = 0;
    if (i < NN){
      u = fkey(p2[i].y);
      hit = (u >= thr);
    }
    uint32_t pos = wave_reserve(hit, &state[CNT_KEY(b)]);
    if (hit && pos < CAND_CAP)
      keys[(size_t)b*CAND_CAP + pos] = ((uint64_t)u << 32) | (uint32_t)(~(uint32_t)i);
  }
}

// ---- per-batch bitonic sort (descending) of 8192 u64 keys in LDS; emit top-6000 ids ----
__global__ __launch_bounds__(1024) void k_sort(char* ws){
  __shared__ uint64_t a[CAND_CAP];
  uint32_t* state = (uint32_t*)ws;
  const uint64_t* kb = (const uint64_t*)(ws + OFF_KEY) + (size_t)blockIdx.x * CAND_CAP;
  uint32_t* sorted = (uint32_t*)(ws + OFF_SORTED);
  int b = blockIdx.x, t = threadIdx.x;
  uint32_t cnt = state[CNT_KEY(b)]; if (cnt > CAND_CAP) cnt = CAND_CAP;
  for (int e = t; e < CAND_CAP; e += 1024) a[e] = (e < (int)cnt) ? kb[e] : 0ull;
  __syncthreads();
  for (int k = 2; k <= CAND_CAP; k <<= 1){
    for (int j = k >> 1; j > 0; j >>= 1){
      for (int e = t; e < CAND_CAP; e += 1024){
        int p = e ^ j;
        if (p > e){
          uint64_t x = a[e], y = a[p];
          bool up = (e & k) == 0;
          if (up ? (x < y) : (x > y)){ a[e] = y; a[p] = x; }
        }
      }
      __syncthreads();
    }
  }
  for (int kk = t; kk < PRE_NMS; kk += 1024){
    uint32_t id = ~(uint32_t)(a[kk] & 0xFFFFFFFFull);
    if (id >= NN) id = 0;
    sorted[b*PRE_NMS + kk] = id;
  }
}

// ---- gather deltas/anchors at sorted ids, regress, clip, precompute areas ----
__global__ void k_gather(const float* __restrict__ boff, const float* __restrict__ anc, char* ws){
#pragma clang fp contract(off)
  int t = blockIdx.x*256 + threadIdx.x;
  if (t >= BATCH*PRE_NMS) return;
  int b = t / PRE_NMS, k = t - b*PRE_NMS;
  const uint32_t* sorted = (const uint32_t*)(ws + OFF_SORTED);
  float4* boxes = (float4*)(ws + OFF_BOXES);
  float* areas = (float*)(ws + OFF_AREAS);
  uint32_t id = sorted[b*PRE_NMS + k];
  float4 d4 = ((const float4*)boff)[(size_t)b*NN + id];
  float4 a4 = ((const float4*)anc )[(size_t)b*NN + id];
  float d0 = d4.x*0.1f, d1 = d4.y*0.1f, d2 = d4.z*0.2f, d3 = d4.w*0.2f;
  float h = a4.z - a4.x;
  float w = a4.w - a4.y;
  float cy = a4.x + 0.5f*h + d0*h;
  float cx = a4.y + 0.5f*w + d1*w;
  float h2 = h * expf(d2);
  float w2 = w * expf(d3);
  float y1 = cy - 0.5f*h2, x1 = cx - 0.5f*w2;
  float y2 = cy + 0.5f*h2, x2 = cx + 0.5f*w2;
  y1 = fminf(fmaxf(y1, 0.f), 1.f);
  x1 = fminf(fmaxf(x1, 0.f), 1.f);
  y2 = fminf(fmaxf(y2, 0.f), 1.f);
  x2 = fminf(fmaxf(x2, 0.f), 1.f);
  boxes[(size_t)b*NPAD + k] = make_float4(y1, x1, y2, x2);
  areas[(size_t)b*NPAD + k] = (y2 - y1) * (x2 - x1);
}

// ---- sparse edge build: all pairs i<j with IoU > 0.7 (tiled 64x64, upper triangle) ----
__global__ __launch_bounds__(64) void k_edges(char* ws){
#pragma clang fp contract(off)
  uint32_t* state = (uint32_t*)ws;
  const float4* boxes = (const float4*)(ws + OFF_BOXES);
  const float* areas = (const float*)(ws + OFF_AREAS);
  uint32_t* edges = (uint32_t*)(ws + OFF_EDGES);
  int b = blockIdx.y, t = threadIdx.x;
  int p = blockIdx.x, ti = 0;
  while (p >= NTILE - ti){ p -= NTILE - ti; ++ti; }   // triangular decode
  int tj = ti + p;
  __shared__ float4 cb[64];
  __shared__ float  ca[64];
  int j0 = tj*64 + t;
  cb[t] = boxes[(size_t)b*NPAD + j0];
  ca[t] = areas[(size_t)b*NPAD + j0];
  __syncthreads();
  int i = ti*64 + t;
  bool rowOk = (i < PRE_NMS);
  float4 bi = rowOk ? boxes[(size_t)b*NPAD + i] : make_float4(0,0,0,0);
  float ai = rowOk ? areas[(size_t)b*NPAD + i] : 0.f;
  for (int jj = 0; jj < 64; ++jj){
    int j = tj*64 + jj;
    bool valid = rowOk && (j > i) && (j < PRE_NMS);
    bool hit = false;
    if (valid){
      float4 bj = cb[jj];
      float yy1 = fmaxf(bi.x, bj.x);
      float xx1 = fmaxf(bi.y, bj.y);
      float yy2 = fminf(bi.z, bj.z);
      float xx2 = fminf(bi.w, bj.w);
      float ih = fmaxf(yy2 - yy1, 0.f);
      float iw = fmaxf(xx2 - xx1, 0.f);
      float inter = ih * iw;
      float uni = ai + ca[jj] - inter + 1e-9f;
      hit = (inter / uni) > 0.7f;
    }
    uint32_t slot = wave_reserve(hit, &state[CNT_EDGE(b)]);
    if (hit && slot < EDGE_CAP)
      edges[(size_t)b*EDGE_CAP + slot] = (uint32_t)i | ((uint32_t)j << 13);
  }
}

// ---- greedy NMS sweep (windowed, sparse-edge driven) ----
__global__ __launch_bounds__(256) void k_scan(char* ws, float* __restrict__ out){
  __shared__ uint32_t deg[NPAD + 1];
  __shared__ uint32_t offs[NPAD + 1];
  __shared__ uint32_t ebuf[EDGE_CAP];      // (i&63)<<16 | j
  __shared__ uint32_t suppr[NW32];
  __shared__ uint32_t part[256];
  __shared__ uint32_t adjlo[64];
  __shared__ uint32_t adjhi[64];
  uint32_t* state = (uint32_t*)ws;
  const uint32_t* eb = (const uint32_t*)(ws + OFF_EDGES) + (size_t)blockIdx.x * EDGE_CAP;
  const float4* boxes = (const float4*)(ws + OFF_BOXES);
  int b = blockIdx.x, t = threadIdx.x;

  for (int i = t; i <= NPAD; i += 256) deg[i] = 0;
  for (int i = t; i < NW32; i += 256) suppr[i] = 0;
  __syncthreads();
  uint32_t E = state[CNT_EDGE(b)]; if (E > EDGE_CAP) E = EDGE_CAP;
  for (uint32_t e = t; e < E; e += 256) atomicAdd(&deg[eb[e] & 0x1FFFu], 1u);
  __syncthreads();
  const int CH = 24;
  uint32_t s = 0;
  for (int k = 0; k < CH; ++k){ int i = t*CH + k; if (i <= NPAD) s += deg[i]; }
  part[t] = s;
  __syncthreads();
  if (t == 0){ uint32_t run = 0; for (int c = 0; c < 256; ++c){ uint32_t v = part[c]; part[c] = run; run += v; } }
  __syncthreads();
  uint32_t run = part[t];
  for (int k = 0; k < CH; ++k){ int i = t*CH + k; if (i <= NPAD){ offs[i] = run; run += deg[i]; } }
  __syncthreads();
  for (int i = t; i <= NPAD; i += 256) deg[i] = 0;
  __syncthreads();
  for (uint32_t e = t; e < E; e += 256){
    uint32_t ed = eb[e];
    uint32_t ii = ed & 0x1FFFu, jj = ed >> 13;
    uint32_t slot = atomicAdd(&deg[ii], 1u);
    ebuf[offs[ii] + slot] = ((ii & 63u) << 16) | jj;
  }
  __syncthreads();
  if (t >= 64) return;
  int lane = t;
  uint32_t nsel = 0;
  for (int w = 0; w < NTILE && nsel < NUM_PROP; ++w){
    int base = w*64;
    adjlo[lane] = 0; adjhi[lane] = 0;
    float4 mybox = boxes[(size_t)b*NPAD + base + lane];
    uint64_t sup = (uint64_t)suppr[2*w] | ((uint64_t)suppr[2*w + 1] << 32);
    uint64_t live = ~sup;
    int valid = PRE_NMS - base;
    if (valid < 64) live &= ((1ull << valid) - 1ull);
    uint32_t r0 = offs[base], r1 = offs[base + 64];
    bool anyIn = false;
    for (uint32_t idx = r0 + (uint32_t)lane; idx < r1; idx += 64){
      uint32_t e = ebuf[idx];
      uint32_t il = e >> 16, j = e & 0xFFFFu;
      if (((live >> il) & 1ull) && j < (uint32_t)(base + 64)){
        uint32_t l2 = j - (uint32_t)base;
        if (l2 < 32) atomicOr(&adjlo[il], 1u << l2);
        else         atomicOr(&adjhi[il], 1u << (l2 - 32));
        anyIn = true;
      }
    }
    anyIn = __any((int)anyIn);
    uint64_t sel;
    if (!anyIn){
      uint32_t cnt = __popcll(live);
      uint32_t remn = NUM_PROP - nsel;
      uint32_t take = cnt < remn ? cnt : remn;
      if (live & (1ull << lane)){
        uint32_t r = __popcll(live & ((1ull << lane) - 1ull));
        if (r < take) ((float4*)out)[(size_t)b*NUM_PROP + nsel + r] = mybox;
      }
      nsel += take;
      sel = live;
    } else {
      uint64_t row = (uint64_t)adjlo[lane] | ((uint64_t)adjhi[lane] << 32);
      uint64_t m = live;
      sel = 0;
      while (m && nsel < NUM_PROP){
        int f = __ffsll((unsigned long long)m) - 1;
        m &= m - 1;
        sel |= 1ull << f;
        if (lane == f) ((float4*)out)[(size_t)b*NUM_PROP + nsel] = mybox;
        nsel++;
        m &= ~shfl64(row, f);
      }
    }
    if (nsel >= NUM_PROP) break;
    for (uint32_t idx = r0 + (uint32_t)lane; idx < r1; idx += 64){
      uint32_t e = ebuf[idx];
      uint32_t il = e >> 16, j = e & 0xFFFFu;
      if (((sel >> il) & 1ull) && j >= (uint32_t)(base + 64))
        atomicOr(&suppr[j >> 5], 1u << (j & 31));
    }
  }
  for (uint32_t r = nsel + (uint32_t)lane; r < NUM_PROP; r += 64)
    ((float4*)out)[(size_t)b*NUM_PROP + r] = make_float4(0.f, 0.f, 0.f, 0.f);
}

extern "C" void kernel_launch(void* const* d_in, const int* in_sizes, int n_in,
                              void* d_out, int out_size, void* d_ws, size_t ws_size,
                              hipStream_t stream){
  const float* probs = (const float*)d_in[0];
  const float* boff  = (const float*)d_in[1];
  const float* anc   = (const float*)d_in[2];
  char* ws = (char*)d_ws;
  float* out = (float*)d_out;

  hipMemsetAsync(ws, 0, OFF_KEY, stream);  // zero state + both histograms
  k_hist1  <<<dim3(128, BATCH), 256, 0, stream>>>(probs, ws);
  k_resolve<<<BATCH, 256, 0, stream>>>(ws, 1);
  k_hist2  <<<dim3(128, BATCH), 256, 0, stream>>>(probs, ws);
  k_resolve<<<BATCH, 256, 0, stream>>>(ws, 2);
  k_compact<<<dim3(128, BATCH), 256, 0, stream>>>(probs, ws);
  k_sort   <<<BATCH, 1024, 0, stream>>>(ws);
  k_gather <<<(BATCH*PRE_NMS + 255)/256, 256, 0, stream>>>(boff, anc, ws);
  k_edges  <<<dim3(NTILE*(NTILE+1)/2, BATCH), 64, 0, stream>>>(ws);
  k_scan   <<<BATCH, 256, 0, stream>>>(ws, out);
}

// Round 5
// 316.576 us; speedup vs baseline: 3.0237x; 1.2241x over previous
//
#include <hip/hip_runtime.h>
#include <stdint.h>

// ProposalLayer: top-6000 select -> bbox regression+clip -> greedy NMS -> 2000 proposals
// B=8, N=261888, all float32.

#define BATCH   8
#define NN      261888
#define PRE_NMS 6000
#define NUM_PROP 2000
#define CAND_CAP 8192
#define EDGE_CAP 16384
#define NTILE   94         // ceil(6000/64)
#define NPAD    6016       // NTILE*64
#define NW32    188

// workspace layout (bytes)
#define OFF_HIST1  4096
#define OFF_HIST2  (OFF_HIST1 + BATCH*4096*4)
#define OFF_KEY    (OFF_HIST2 + BATCH*4096*4)          // memset covers [0, OFF_KEY)
#define OFF_SORTED (OFF_KEY + BATCH*CAND_CAP*8)
#define OFF_BOXES  (OFF_SORTED + BATCH*PRE_NMS*4)
#define OFF_AREAS  (OFF_BOXES + BATCH*NPAD*16)
#define OFF_EDGES  (OFF_AREAS + BATCH*NPAD*4)
#define WS_NEED    (OFF_EDGES + BATCH*EDGE_CAP*4)      // ~2.47 MB

// state u32 indices: [b]=L1 bin, [8+b]=Krem, [16+b]=threshold.
// Counters spread 128B (32 u32) apart: one cache line per batch.
#define CNT_KEY(b)   (64  + (b)*32)
#define CNT_EDGE(b)  (320 + (b)*32)

__device__ __forceinline__ uint32_t fkey(float s){
  uint32_t b = __float_as_uint(s);
  return (b & 0x80000000u) ? ~b : (b | 0x80000000u);   // order-preserving float->u32
}

__device__ __forceinline__ uint64_t shfl64(uint64_t v, int src){
  uint32_t lo = __shfl((uint32_t)(v & 0xFFFFFFFFull), src, 64);
  uint32_t hi = __shfl((uint32_t)(v >> 32), src, 64);
  return (uint64_t)lo | ((uint64_t)hi << 32);
}

// wave-aggregated counter reservation: one atomic per wave instead of per lane.
__device__ __forceinline__ uint32_t wave_reserve(bool pred, uint32_t* ctr){
  uint64_t m = __ballot((int)pred);
  if (!m) return 0xFFFFFFFFu;
  int lane = (int)(threadIdx.x & 63u);
  int leader = __ffsll((unsigned long long)m) - 1;
  uint32_t base = 0;
  if (lane == leader) base = atomicAdd(ctr, (uint32_t)__popcll(m));
  base = __shfl(base, leader, 64);
  return base + (uint32_t)__popcll(m & ((1ull << lane) - 1ull));
}

// ---- level-1 histogram of top 12 bits of fkey ----
__global__ void k_hist1(const float* __restrict__ probs, char* ws){
  __shared__ uint32_t h[4096];
  int b = blockIdx.y;
  for (int t = threadIdx.x; t < 4096; t += 256) h[t] = 0;
  __syncthreads();
  const float2* p2 = (const float2*)probs + (size_t)b * NN;
  int base = blockIdx.x * 2048;
  for (int k = 0; k < 8; ++k){
    int i = base + k*256 + threadIdx.x;
    if (i < NN) atomicAdd(&h[fkey(p2[i].y) >> 20], 1u);
  }
  __syncthreads();
  uint32_t* gh = (uint32_t*)(ws + OFF_HIST1) + b*4096;
  for (int t = threadIdx.x; t < 4096; t += 256) if (h[t]) atomicAdd(&gh[t], h[t]);
}

// ---- level-2 histogram (bits 19:8) among elements matching L1 prefix ----
__global__ void k_hist2(const float* __restrict__ probs, char* ws){
  __shared__ uint32_t h[4096];
  uint32_t* state = (uint32_t*)ws;
  int b = blockIdx.y;
  uint32_t pref = state[b];
  for (int t = threadIdx.x; t < 4096; t += 256) h[t] = 0;
  __syncthreads();
  const float2* p2 = (const float2*)probs + (size_t)b * NN;
  int base = blockIdx.x * 2048;
  for (int k = 0; k < 8; ++k){
    int i = base + k*256 + threadIdx.x;
    if (i < NN){
      uint32_t u = fkey(p2[i].y);
      if ((u >> 20) == pref) atomicAdd(&h[(u >> 8) & 0xFFFu], 1u);
    }
  }
  __syncthreads();
  uint32_t* gh = (uint32_t*)(ws + OFF_HIST2) + b*4096;
  for (int t = threadIdx.x; t < 4096; t += 256) if (h[t]) atomicAdd(&gh[t], h[t]);
}

// ---- find histogram bin where cumulative-from-top crosses K ----
__global__ void k_resolve(char* ws, int level){
  uint32_t* state = (uint32_t*)ws;
  const uint32_t* gh = (const uint32_t*)(ws + (level == 1 ? OFF_HIST1 : OFF_HIST2)) + blockIdx.x*4096;
  __shared__ uint32_t part[256];
  int b = blockIdx.x, t = threadIdx.x;
  uint32_t s = 0;
  for (int k = 0; k < 16; ++k) s += gh[t*16 + k];
  part[t] = s;
  __syncthreads();
  if (t == 0){
    uint32_t K = (level == 1) ? (uint32_t)PRE_NMS : state[8 + b];
    uint32_t cum = 0; int c = 255;
    for (; c > 0; --c){ if (cum + part[c] >= K) break; cum += part[c]; }
    uint32_t rem = K - cum;
    uint32_t cum2 = 0; int bin = c*16;
    for (int k = 15; k >= 0; --k){
      uint32_t v = gh[c*16 + k];
      if (cum2 + v >= rem){ bin = c*16 + k; rem = rem - cum2; break; }
      cum2 += v;
    }
    if (level == 1){ state[b] = (uint32_t)bin; state[8 + b] = rem; }
    else           { state[16 + b] = (state[b] << 20) | ((uint32_t)bin << 8); }
  }
}

// ---- compact all elements with fkey >= threshold into distinct u64 keys ----
__global__ void k_compact(const float* __restrict__ probs, char* ws){
  uint32_t* state = (uint32_t*)ws;
  uint64_t* keys = (uint64_t*)(ws + OFF_KEY);
  int b = blockIdx.y;
  uint32_t thr = state[16 + b];
  const float2* p2 = (const float2*)probs + (size_t)b * NN;
  int base = blockIdx.x * 2048;
  for (int k = 0; k < 8; ++k){
    int i = base + k*256 + threadIdx.x;
    bool hit = false; uint32_t u = 0;
    if (i < NN){
      u = fkey(p2[i].y);
      hit = (u >= thr);
    }
    uint32_t pos = wave_reserve(hit, &state[CNT_KEY(b)]);
    if (hit && pos < CAND_CAP)
      keys[(size_t)b*CAND_CAP + pos] = ((uint64_t)u << 32) | (uint32_t)(~(uint32_t)i);
  }
}

// ---- rank-sort: rank = #{keys > mine}; scatter id to sorted[rank] if rank < 6000 ----
// Keys are distinct u64 -> ranks unique -> every slot 0..5999 written exactly once
// (cnt >= 6000 by threshold construction). Pad/stale entries excluded via cnt.
__global__ __launch_bounds__(256) void k_rank(char* ws){
  __shared__ uint64_t tile[1024];
  uint32_t* state = (uint32_t*)ws;
  int b = blockIdx.y, t = threadIdx.x;
  uint32_t cnt = state[CNT_KEY(b)]; if (cnt > CAND_CAP) cnt = CAND_CAP;
  const uint64_t* kb = (const uint64_t*)(ws + OFF_KEY) + (size_t)b * CAND_CAP;
  uint32_t* sorted = (uint32_t*)(ws + OFF_SORTED);
  int kidx = blockIdx.x*256 + t;
  uint64_t my = (kidx < (int)cnt) ? kb[kidx] : 0ull;
  uint32_t r0 = 0, r1 = 0, r2 = 0, r3 = 0;
  for (int base = 0; base < CAND_CAP; base += 1024){
    for (int e = t; e < 1024; e += 256){
      int g = base + e;
      tile[e] = (g < (int)cnt) ? kb[g] : 0ull;   // 0 < any real key (real keys have bit63 set)
    }
    __syncthreads();
    int lim = (int)cnt - base; if (lim < 0) lim = 0; if (lim > 1024) lim = 1024;
    int lim4 = lim & ~3;
    for (int e = 0; e < lim4; e += 4){
      r0 += (tile[e]   > my) ? 1u : 0u;
      r1 += (tile[e+1] > my) ? 1u : 0u;
      r2 += (tile[e+2] > my) ? 1u : 0u;
      r3 += (tile[e+3] > my) ? 1u : 0u;
    }
    for (int e = lim4; e < lim; ++e) r0 += (tile[e] > my) ? 1u : 0u;
    __syncthreads();
  }
  uint32_t rank = r0 + r1 + r2 + r3;
  if (kidx < (int)cnt && rank < PRE_NMS){
    uint32_t id = ~(uint32_t)(my & 0xFFFFFFFFull);
    sorted[b*PRE_NMS + rank] = id;
  }
}

// ---- gather deltas/anchors at sorted ids, regress, clip, precompute areas ----
__global__ void k_gather(const float* __restrict__ boff, const float* __restrict__ anc, char* ws){
#pragma clang fp contract(off)
  int t = blockIdx.x*256 + threadIdx.x;
  if (t >= BATCH*PRE_NMS) return;
  int b = t / PRE_NMS, k = t - b*PRE_NMS;
  const uint32_t* sorted = (const uint32_t*)(ws + OFF_SORTED);
  float4* boxes = (float4*)(ws + OFF_BOXES);
  float* areas = (float*)(ws + OFF_AREAS);
  uint32_t id = sorted[b*PRE_NMS + k];
  float4 d4 = ((const float4*)boff)[(size_t)b*NN + id];
  float4 a4 = ((const float4*)anc )[(size_t)b*NN + id];
  float d0 = d4.x*0.1f, d1 = d4.y*0.1f, d2 = d4.z*0.2f, d3 = d4.w*0.2f;
  float h = a4.z - a4.x;
  float w = a4.w - a4.y;
  float cy = a4.x + 0.5f*h + d0*h;
  float cx = a4.y + 0.5f*w + d1*w;
  float h2 = h * expf(d2);
  float w2 = w * expf(d3);
  float y1 = cy - 0.5f*h2, x1 = cx - 0.5f*w2;
  float y2 = cy + 0.5f*h2, x2 = cx + 0.5f*w2;
  y1 = fminf(fmaxf(y1, 0.f), 1.f);
  x1 = fminf(fmaxf(x1, 0.f), 1.f);
  y2 = fminf(fmaxf(y2, 0.f), 1.f);
  x2 = fminf(fmaxf(x2, 0.f), 1.f);
  boxes[(size_t)b*NPAD + k] = make_float4(y1, x1, y2, x2);
  areas[(size_t)b*NPAD + k] = (y2 - y1) * (x2 - x1);
}

// ---- sparse edge build: all pairs i<j with IoU > 0.7 (tiled 64x64, upper triangle) ----
__global__ __launch_bounds__(64) void k_edges(char* ws){
#pragma clang fp contract(off)
  uint32_t* state = (uint32_t*)ws;
  const float4* boxes = (const float4*)(ws + OFF_BOXES);
  const float* areas = (const float*)(ws + OFF_AREAS);
  uint32_t* edges = (uint32_t*)(ws + OFF_EDGES);
  int b = blockIdx.y, t = threadIdx.x;
  int p = blockIdx.x, ti = 0;
  while (p >= NTILE - ti){ p -= NTILE - ti; ++ti; }   // triangular decode
  int tj = ti + p;
  __shared__ float4 cb[64];
  __shared__ float  ca[64];
  int j0 = tj*64 + t;
  cb[t] = boxes[(size_t)b*NPAD + j0];
  ca[t] = areas[(size_t)b*NPAD + j0];
  __syncthreads();
  int i = ti*64 + t;
  bool rowOk = (i < PRE_NMS);
  float4 bi = rowOk ? boxes[(size_t)b*NPAD + i] : make_float4(0,0,0,0);
  float ai = rowOk ? areas[(size_t)b*NPAD + i] : 0.f;
  for (int jj = 0; jj < 64; ++jj){
    int j = tj*64 + jj;
    bool valid = rowOk && (j > i) && (j < PRE_NMS);
    bool hit = false;
    if (valid){
      float4 bj = cb[jj];
      float yy1 = fmaxf(bi.x, bj.x);
      float xx1 = fmaxf(bi.y, bj.y);
      float yy2 = fminf(bi.z, bj.z);
      float xx2 = fminf(bi.w, bj.w);
      float ih = fmaxf(yy2 - yy1, 0.f);
      float iw = fmaxf(xx2 - xx1, 0.f);
      float inter = ih * iw;
      float uni = ai + ca[jj] - inter + 1e-9f;
      hit = (inter / uni) > 0.7f;
    }
    uint32_t slot = wave_reserve(hit, &state[CNT_EDGE(b)]);
    if (hit && slot < EDGE_CAP)
      edges[(size_t)b*EDGE_CAP + slot] = (uint32_t)i | ((uint32_t)j << 13);
  }
}

// ---- greedy NMS sweep (windowed, sparse-edge driven) ----
__global__ __launch_bounds__(256) void k_scan(char* ws, float* __restrict__ out){
  __shared__ uint32_t deg[NPAD + 1];
  __shared__ uint32_t offs[NPAD + 1];
  __shared__ uint32_t ebuf[EDGE_CAP];      // (i&63)<<16 | j
  __shared__ uint32_t suppr[NW32];
  __shared__ uint32_t part[256];
  __shared__ uint32_t adjlo[64];
  __shared__ uint32_t adjhi[64];
  uint32_t* state = (uint32_t*)ws;
  const uint32_t* eb = (const uint32_t*)(ws + OFF_EDGES) + (size_t)blockIdx.x * EDGE_CAP;
  const float4* boxes = (const float4*)(ws + OFF_BOXES);
  int b = blockIdx.x, t = threadIdx.x;

  for (int i = t; i <= NPAD; i += 256) deg[i] = 0;
  for (int i = t; i < NW32; i += 256) suppr[i] = 0;
  __syncthreads();
  uint32_t E = state[CNT_EDGE(b)]; if (E > EDGE_CAP) E = EDGE_CAP;
  for (uint32_t e = t; e < E; e += 256) atomicAdd(&deg[eb[e] & 0x1FFFu], 1u);
  __syncthreads();
  const int CH = 24;
  uint32_t s = 0;
  for (int k = 0; k < CH; ++k){ int i = t*CH + k; if (i <= NPAD) s += deg[i]; }
  part[t] = s;
  __syncthreads();
  if (t == 0){ uint32_t run = 0; for (int c = 0; c < 256; ++c){ uint32_t v = part[c]; part[c] = run; run += v; } }
  __syncthreads();
  uint32_t run = part[t];
  for (int k = 0; k < CH; ++k){ int i = t*CH + k; if (i <= NPAD){ offs[i] = run; run += deg[i]; } }
  __syncthreads();
  for (int i = t; i <= NPAD; i += 256) deg[i] = 0;
  __syncthreads();
  for (uint32_t e = t; e < E; e += 256){
    uint32_t ed = eb[e];
    uint32_t ii = ed & 0x1FFFu, jj = ed >> 13;
    uint32_t slot = atomicAdd(&deg[ii], 1u);
    ebuf[offs[ii] + slot] = ((ii & 63u) << 16) | jj;
  }
  __syncthreads();
  if (t >= 64) return;
  int lane = t;
  uint32_t nsel = 0;
  for (int w = 0; w < NTILE && nsel < NUM_PROP; ++w){
    int base = w*64;
    adjlo[lane] = 0; adjhi[lane] = 0;
    float4 mybox = boxes[(size_t)b*NPAD + base + lane];
    uint64_t sup = (uint64_t)suppr[2*w] | ((uint64_t)suppr[2*w + 1] << 32);
    uint64_t live = ~sup;
    int valid = PRE_NMS - base;
    if (valid < 64) live &= ((1ull << valid) - 1ull);
    uint32_t r0 = offs[base], r1 = offs[base + 64];
    bool anyIn = false;
    for (uint32_t idx = r0 + (uint32_t)lane; idx < r1; idx += 64){
      uint32_t e = ebuf[idx];
      uint32_t il = e >> 16, j = e & 0xFFFFu;
      if (((live >> il) & 1ull) && j < (uint32_t)(base + 64)){
        uint32_t l2 = j - (uint32_t)base;
        if (l2 < 32) atomicOr(&adjlo[il], 1u << l2);
        else         atomicOr(&adjhi[il], 1u << (l2 - 32));
        anyIn = true;
      }
    }
    anyIn = __any((int)anyIn);
    uint64_t sel;
    if (!anyIn){
      uint32_t cnt = __popcll(live);
      uint32_t remn = NUM_PROP - nsel;
      uint32_t take = cnt < remn ? cnt : remn;
      if (live & (1ull << lane)){
        uint32_t r = __popcll(live & ((1ull << lane) - 1ull));
        if (r < take) ((float4*)out)[(size_t)b*NUM_PROP + nsel + r] = mybox;
      }
      nsel += take;
      sel = live;
    } else {
      uint64_t row = (uint64_t)adjlo[lane] | ((uint64_t)adjhi[lane] << 32);
      uint64_t m = live;
      sel = 0;
      while (m && nsel < NUM_PROP){
        int f = __ffsll((unsigned long long)m) - 1;
        m &= m - 1;
        sel |= 1ull << f;
        if (lane == f) ((float4*)out)[(size_t)b*NUM_PROP + nsel] = mybox;
        nsel++;
        m &= ~shfl64(row, f);
      }
    }
    if (nsel >= NUM_PROP) break;
    for (uint32_t idx = r0 + (uint32_t)lane; idx < r1; idx += 64){
      uint32_t e = ebuf[idx];
      uint32_t il = e >> 16, j = e & 0xFFFFu;
      if (((sel >> il) & 1ull) && j >= (uint32_t)(base + 64))
        atomicOr(&suppr[j >> 5], 1u << (j & 31));
    }
  }
  for (uint32_t r = nsel + (uint32_t)lane; r < NUM_PROP; r += 64)
    ((float4*)out)[(size_t)b*NUM_PROP + r] = make_float4(0.f, 0.f, 0.f, 0.f);
}

extern "C" void kernel_launch(void* const* d_in, const int* in_sizes, int n_in,
                              void* d_out, int out_size, void* d_ws, size_t ws_size,
                              hipStream_t stream){
  const float* probs = (const float*)d_in[0];
  const float* boff  = (const float*)d_in[1];
  const float* anc   = (const float*)d_in[2];
  char* ws = (char*)d_ws;
  float* out = (float*)d_out;

  hipMemsetAsync(ws, 0, OFF_KEY, stream);  // zero state + both histograms
  k_hist1  <<<dim3(128, BATCH), 256, 0, stream>>>(probs, ws);
  k_resolve<<<BATCH, 256, 0, stream>>>(ws, 1);
  k_hist2  <<<dim3(128, BATCH), 256, 0, stream>>>(probs, ws);
  k_resolve<<<BATCH, 256, 0, stream>>>(ws, 2);
  k_compact<<<dim3(128, BATCH), 256, 0, stream>>>(probs, ws);
  k_rank   <<<dim3(CAND_CAP/256, BATCH), 256, 0, stream>>>(ws);
  k_gather <<<(BATCH*PRE_NMS + 255)/256, 256, 0, stream>>>(boff, anc, ws);
  k_edges  <<<dim3(NTILE*(NTILE+1)/2, BATCH), 64, 0, stream>>>(ws);
  k_scan   <<<BATCH, 256, 0, stream>>>(ws, out);
}

// Round 6
// 292.856 us; speedup vs baseline: 3.2686x; 1.0810x over previous
//
#include <hip/hip_runtime.h>
#include <stdint.h>

// ProposalLayer: top-6000 select -> bbox regression+clip -> greedy NMS -> 2000 proposals
// B=8, N=261888, all float32.

#define BATCH   8
#define NN      261888
#define PRE_NMS 6000
#define NUM_PROP 2000
#define CAND_CAP 8192
#define EDGE_CAP 16384
#define NTILE   94         // ceil(6000/64)
#define NPAD    6016       // NTILE*64
#define NW32    188

// workspace layout (bytes)
#define OFF_HIST1  4096
#define OFF_HIST2  (OFF_HIST1 + BATCH*4096*4)
#define OFF_KEY    (OFF_HIST2 + BATCH*4096*4)          // memset covers [0, OFF_KEY)
#define OFF_SORTED (OFF_KEY + BATCH*CAND_CAP*8)
#define OFF_BOXES  (OFF_SORTED + BATCH*PRE_NMS*4)
#define OFF_AREAS  (OFF_BOXES + BATCH*NPAD*16)
#define OFF_EDGES  (OFF_AREAS + BATCH*NPAD*4)
#define WS_NEED    (OFF_EDGES + BATCH*EDGE_CAP*4)      // ~2.47 MB

// state u32 indices: [b]=L1 bin, [8+b]=Krem, [16+b]=threshold.
// Counters spread 128B (32 u32) apart: one cache line per batch.
#define CNT_KEY(b)   (64  + (b)*32)
#define CNT_EDGE(b)  (320 + (b)*32)

__device__ __forceinline__ uint32_t fkey(float s){
  uint32_t b = __float_as_uint(s);
  return (b & 0x80000000u) ? ~b : (b | 0x80000000u);   // order-preserving float->u32
}

__device__ __forceinline__ uint64_t shfl64(uint64_t v, int src){
  uint32_t lo = __shfl((uint32_t)(v & 0xFFFFFFFFull), src, 64);
  uint32_t hi = __shfl((uint32_t)(v >> 32), src, 64);
  return (uint64_t)lo | ((uint64_t)hi << 32);
}

// wave-aggregated counter reservation: one atomic per wave instead of per lane.
__device__ __forceinline__ uint32_t wave_reserve(bool pred, uint32_t* ctr){
  uint64_t m = __ballot((int)pred);
  if (!m) return 0xFFFFFFFFu;
  int lane = (int)(threadIdx.x & 63u);
  int leader = __ffsll((unsigned long long)m) - 1;
  uint32_t base = 0;
  if (lane == leader) base = atomicAdd(ctr, (uint32_t)__popcll(m));
  base = __shfl(base, leader, 64);
  return base + (uint32_t)__popcll(m & ((1ull << lane) - 1ull));
}

// ---- level-1 histogram of top 12 bits of fkey ----
__global__ void k_hist1(const float* __restrict__ probs, char* ws){
  __shared__ uint32_t h[4096];
  int b = blockIdx.y;
  for (int t = threadIdx.x; t < 4096; t += 256) h[t] = 0;
  __syncthreads();
  const float2* p2 = (const float2*)probs + (size_t)b * NN;
  int base = blockIdx.x * 2048;
  for (int k = 0; k < 8; ++k){
    int i = base + k*256 + threadIdx.x;
    if (i < NN) atomicAdd(&h[fkey(p2[i].y) >> 20], 1u);
  }
  __syncthreads();
  uint32_t* gh = (uint32_t*)(ws + OFF_HIST1) + b*4096;
  for (int t = threadIdx.x; t < 4096; t += 256) if (h[t]) atomicAdd(&gh[t], h[t]);
}

// ---- level-2 histogram (bits 19:8) among elements matching L1 prefix ----
__global__ void k_hist2(const float* __restrict__ probs, char* ws){
  __shared__ uint32_t h[4096];
  uint32_t* state = (uint32_t*)ws;
  int b = blockIdx.y;
  uint32_t pref = state[b];
  for (int t = threadIdx.x; t < 4096; t += 256) h[t] = 0;
  __syncthreads();
  const float2* p2 = (const float2*)probs + (size_t)b * NN;
  int base = blockIdx.x * 2048;
  for (int k = 0; k < 8; ++k){
    int i = base + k*256 + threadIdx.x;
    if (i < NN){
      uint32_t u = fkey(p2[i].y);
      if ((u >> 20) == pref) atomicAdd(&h[(u >> 8) & 0xFFFu], 1u);
    }
  }
  __syncthreads();
  uint32_t* gh = (uint32_t*)(ws + OFF_HIST2) + b*4096;
  for (int t = threadIdx.x; t < 4096; t += 256) if (h[t]) atomicAdd(&gh[t], h[t]);
}

// ---- find histogram bin where cumulative-from-top crosses K ----
__global__ void k_resolve(char* ws, int level){
  uint32_t* state = (uint32_t*)ws;
  const uint32_t* gh = (const uint32_t*)(ws + (level == 1 ? OFF_HIST1 : OFF_HIST2)) + blockIdx.x*4096;
  __shared__ uint32_t part[256];
  int b = blockIdx.x, t = threadIdx.x;
  uint32_t s = 0;
  for (int k = 0; k < 16; ++k) s += gh[t*16 + k];
  part[t] = s;
  __syncthreads();
  if (t == 0){
    uint32_t K = (level == 1) ? (uint32_t)PRE_NMS : state[8 + b];
    uint32_t cum = 0; int c = 255;
    for (; c > 0; --c){ if (cum + part[c] >= K) break; cum += part[c]; }
    uint32_t rem = K - cum;
    uint32_t cum2 = 0; int bin = c*16;
    for (int k = 15; k >= 0; --k){
      uint32_t v = gh[c*16 + k];
      if (cum2 + v >= rem){ bin = c*16 + k; rem = rem - cum2; break; }
      cum2 += v;
    }
    if (level == 1){ state[b] = (uint32_t)bin; state[8 + b] = rem; }
    else           { state[16 + b] = (state[b] << 20) | ((uint32_t)bin << 8); }
  }
}

// ---- compact all elements with fkey >= threshold into distinct u64 keys ----
__global__ void k_compact(const float* __restrict__ probs, char* ws){
  uint32_t* state = (uint32_t*)ws;
  uint64_t* keys = (uint64_t*)(ws + OFF_KEY);
  int b = blockIdx.y;
  uint32_t thr = state[16 + b];
  const float2* p2 = (const float2*)probs + (size_t)b * NN;
  int base = blockIdx.x * 2048;
  for (int k = 0; k < 8; ++k){
    int i = base + k*256 + threadIdx.x;
    bool hit = false; uint32_t u = 0;
    if (i < NN){
      u = fkey(p2[i].y);
      hit = (u >= thr);
    }
    uint32_t pos = wave_reserve(hit, &state[CNT_KEY(b)]);
    if (hit && pos < CAND_CAP)
      keys[(size_t)b*CAND_CAP + pos] = ((uint64_t)u << 32) | (uint32_t)(~(uint32_t)i);
  }
}

// ---- rank-sort: rank = #{keys > mine}; scatter id to sorted[rank] if rank < 6000 ----
__global__ __launch_bounds__(256) void k_rank(char* ws){
  __shared__ uint64_t tile[1024];
  uint32_t* state = (uint32_t*)ws;
  int b = blockIdx.y, t = threadIdx.x;
  uint32_t cnt = state[CNT_KEY(b)]; if (cnt > CAND_CAP) cnt = CAND_CAP;
  const uint64_t* kb = (const uint64_t*)(ws + OFF_KEY) + (size_t)b * CAND_CAP;
  uint32_t* sorted = (uint32_t*)(ws + OFF_SORTED);
  int kidx = blockIdx.x*256 + t;
  uint64_t my = (kidx < (int)cnt) ? kb[kidx] : 0ull;
  uint32_t r0 = 0, r1 = 0, r2 = 0, r3 = 0;
  for (int base = 0; base < CAND_CAP; base += 1024){
    for (int e = t; e < 1024; e += 256){
      int g = base + e;
      tile[e] = (g < (int)cnt) ? kb[g] : 0ull;
    }
    __syncthreads();
    int lim = (int)cnt - base; if (lim < 0) lim = 0; if (lim > 1024) lim = 1024;
    int lim4 = lim & ~3;
    for (int e = 0; e < lim4; e += 4){
      r0 += (tile[e]   > my) ? 1u : 0u;
      r1 += (tile[e+1] > my) ? 1u : 0u;
      r2 += (tile[e+2] > my) ? 1u : 0u;
      r3 += (tile[e+3] > my) ? 1u : 0u;
    }
    for (int e = lim4; e < lim; ++e) r0 += (tile[e] > my) ? 1u : 0u;
    __syncthreads();
  }
  uint32_t rank = r0 + r1 + r2 + r3;
  if (kidx < (int)cnt && rank < PRE_NMS){
    uint32_t id = ~(uint32_t)(my & 0xFFFFFFFFull);
    sorted[b*PRE_NMS + rank] = id;
  }
}

// ---- gather deltas/anchors at sorted ids, regress, clip, precompute areas ----
__global__ void k_gather(const float* __restrict__ boff, const float* __restrict__ anc, char* ws){
#pragma clang fp contract(off)
  int t = blockIdx.x*256 + threadIdx.x;
  if (t >= BATCH*PRE_NMS) return;
  int b = t / PRE_NMS, k = t - b*PRE_NMS;
  const uint32_t* sorted = (const uint32_t*)(ws + OFF_SORTED);
  float4* boxes = (float4*)(ws + OFF_BOXES);
  float* areas = (float*)(ws + OFF_AREAS);
  uint32_t id = sorted[b*PRE_NMS + k];
  float4 d4 = ((const float4*)boff)[(size_t)b*NN + id];
  float4 a4 = ((const float4*)anc )[(size_t)b*NN + id];
  float d0 = d4.x*0.1f, d1 = d4.y*0.1f, d2 = d4.z*0.2f, d3 = d4.w*0.2f;
  float h = a4.z - a4.x;
  float w = a4.w - a4.y;
  float cy = a4.x + 0.5f*h + d0*h;
  float cx = a4.y + 0.5f*w + d1*w;
  float h2 = h * expf(d2);
  float w2 = w * expf(d3);
  float y1 = cy - 0.5f*h2, x1 = cx - 0.5f*w2;
  float y2 = cy + 0.5f*h2, x2 = cx + 0.5f*w2;
  y1 = fminf(fmaxf(y1, 0.f), 1.f);
  x1 = fminf(fmaxf(x1, 0.f), 1.f);
  y2 = fminf(fmaxf(y2, 0.f), 1.f);
  x2 = fminf(fmaxf(x2, 0.f), 1.f);
  boxes[(size_t)b*NPAD + k] = make_float4(y1, x1, y2, x2);
  areas[(size_t)b*NPAD + k] = (y2 - y1) * (x2 - x1);
}

// ---- sparse edge build: all pairs i<j with IoU > 0.7 (tiled 64x64, upper triangle) ----
// Division-free exact threshold test: for uni>0,
//   RN32(inter/uni) > 0.7f  <=>  inter >= M*uni in reals, M = midpoint(0.7f, nextup(0.7f))
// (tie q==M rounds to even mantissa 0x...34 > 0.7f, so >= includes it).
// M*(double)uni is EXACT (25+24 = 49 <= 53 mantissa bits) -> decision bit-identical
// to the f32-division version that passed rounds 1-5.
__global__ __launch_bounds__(64) void k_edges(char* ws){
#pragma clang fp contract(off)
  const double M = 0x1.666667p-1;        // 0.7000000178813934326171875
  uint32_t* state = (uint32_t*)ws;
  const float4* boxes = (const float4*)(ws + OFF_BOXES);
  const float* areas = (const float*)(ws + OFF_AREAS);
  uint32_t* edges = (uint32_t*)(ws + OFF_EDGES);
  int b = blockIdx.y, t = threadIdx.x;
  int p = blockIdx.x, ti = 0;
  while (p >= NTILE - ti){ p -= NTILE - ti; ++ti; }   // triangular decode
  int tj = ti + p;
  __shared__ float4 cb[64];
  __shared__ float  ca[64];
  int j0 = tj*64 + t;
  cb[t] = boxes[(size_t)b*NPAD + j0];
  ca[t] = areas[(size_t)b*NPAD + j0];
  __syncthreads();
  int i = ti*64 + t;
  bool rowOk = (i < PRE_NMS);
  float4 bi = rowOk ? boxes[(size_t)b*NPAD + i] : make_float4(0,0,0,0);
  float ai = rowOk ? areas[(size_t)b*NPAD + i] : 0.f;
  // validity masks: j must satisfy j>i and j<PRE_NMS. Out-of-range boxes are
  // zeros (area 0) -> inter=0, condition 0 >= M*(0+1e-9) false; but enforce
  // masks anyway for exactness.
  uint64_t hitmask = 0;
  if (rowOk){
#pragma unroll 8
    for (int jj = 0; jj < 64; ++jj){
      int j = tj*64 + jj;
      float4 bj = cb[jj];
      float yy1 = fmaxf(bi.x, bj.x);
      float xx1 = fmaxf(bi.y, bj.y);
      float yy2 = fminf(bi.z, bj.z);
      float xx2 = fminf(bi.w, bj.w);
      float ih = fmaxf(yy2 - yy1, 0.f);
      float iw = fmaxf(xx2 - xx1, 0.f);
      float inter = ih * iw;
      float uni = ai + ca[jj] - inter + 1e-9f;
      bool hit = ((double)inter >= M * (double)uni) && (j > i) && (j < PRE_NMS);
      hitmask |= hit ? (1ull << jj) : 0ull;
    }
  }
  // drain: hits are rare (avg < 1 per wave), so this loop runs ~0-1 times.
  while (__any((int)(hitmask != 0ull))){
    bool pred = hitmask != 0ull;
    int jj = pred ? (__ffsll((unsigned long long)hitmask) - 1) : 0;
    uint32_t slot = wave_reserve(pred, &state[CNT_EDGE(b)]);
    if (pred && slot < EDGE_CAP)
      edges[(size_t)b*EDGE_CAP + slot] = (uint32_t)i | ((uint32_t)(tj*64 + jj) << 13);
    hitmask &= hitmask - 1;
  }
}

// ---- greedy NMS sweep (windowed, sparse-edge driven) ----
__global__ __launch_bounds__(256) void k_scan(char* ws, float* __restrict__ out){
  __shared__ uint32_t deg[NPAD + 1];
  __shared__ uint32_t offs[NPAD + 1];
  __shared__ uint32_t ebuf[EDGE_CAP];      // (i&63)<<16 | j
  __shared__ uint32_t suppr[NW32];
  __shared__ uint32_t part[256];
  __shared__ uint32_t adjlo[64];
  __shared__ uint32_t adjhi[64];
  uint32_t* state = (uint32_t*)ws;
  const uint32_t* eb = (const uint32_t*)(ws + OFF_EDGES) + (size_t)blockIdx.x * EDGE_CAP;
  const float4* boxes = (const float4*)(ws + OFF_BOXES);
  int b = blockIdx.x, t = threadIdx.x;

  for (int i = t; i <= NPAD; i += 256) deg[i] = 0;
  for (int i = t; i < NW32; i += 256) suppr[i] = 0;
  __syncthreads();
  uint32_t E = state[CNT_EDGE(b)]; if (E > EDGE_CAP) E = EDGE_CAP;
  for (uint32_t e = t; e < E; e += 256) atomicAdd(&deg[eb[e] & 0x1FFFu], 1u);
  __syncthreads();
  const int CH = 24;
  uint32_t s = 0;
  for (int k = 0; k < CH; ++k){ int i = t*CH + k; if (i <= NPAD) s += deg[i]; }
  part[t] = s;
  __syncthreads();
  if (t == 0){ uint32_t run = 0; for (int c = 0; c < 256; ++c){ uint32_t v = part[c]; part[c] = run; run += v; } }
  __syncthreads();
  uint32_t run = part[t];
  for (int k = 0; k < CH; ++k){ int i = t*CH + k; if (i <= NPAD){ offs[i] = run; run += deg[i]; } }
  __syncthreads();
  for (int i = t; i <= NPAD; i += 256) deg[i] = 0;
  __syncthreads();
  for (uint32_t e = t; e < E; e += 256){
    uint32_t ed = eb[e];
    uint32_t ii = ed & 0x1FFFu, jj = ed >> 13;
    uint32_t slot = atomicAdd(&deg[ii], 1u);
    ebuf[offs[ii] + slot] = ((ii & 63u) << 16) | jj;
  }
  __syncthreads();
  if (t >= 64) return;
  int lane = t;
  uint32_t nsel = 0;
  for (int w = 0; w < NTILE && nsel < NUM_PROP; ++w){
    int base = w*64;
    adjlo[lane] = 0; adjhi[lane] = 0;
    float4 mybox = boxes[(size_t)b*NPAD + base + lane];
    uint64_t sup = (uint64_t)suppr[2*w] | ((uint64_t)suppr[2*w + 1] << 32);
    uint64_t live = ~sup;
    int valid = PRE_NMS - base;
    if (valid < 64) live &= ((1ull << valid) - 1ull);
    uint32_t r0 = offs[base], r1 = offs[base + 64];
    bool anyIn = false;
    for (uint32_t idx = r0 + (uint32_t)lane; idx < r1; idx += 64){
      uint32_t e = ebuf[idx];
      uint32_t il = e >> 16, j = e & 0xFFFFu;
      if (((live >> il) & 1ull) && j < (uint32_t)(base + 64)){
        uint32_t l2 = j - (uint32_t)base;
        if (l2 < 32) atomicOr(&adjlo[il], 1u << l2);
        else         atomicOr(&adjhi[il], 1u << (l2 - 32));
        anyIn = true;
      }
    }
    anyIn = __any((int)anyIn);
    uint64_t sel;
    if (!anyIn){
      uint32_t cnt = __popcll(live);
      uint32_t remn = NUM_PROP - nsel;
      uint32_t take = cnt < remn ? cnt : remn;
      if (live & (1ull << lane)){
        uint32_t r = __popcll(live & ((1ull << lane) - 1ull));
        if (r < take) ((float4*)out)[(size_t)b*NUM_PROP + nsel + r] = mybox;
      }
      nsel += take;
      sel = live;
    } else {
      uint64_t row = (uint64_t)adjlo[lane] | ((uint64_t)adjhi[lane] << 32);
      uint64_t m = live;
      sel = 0;
      while (m && nsel < NUM_PROP){
        int f = __ffsll((unsigned long long)m) - 1;
        m &= m - 1;
        sel |= 1ull << f;
        if (lane == f) ((float4*)out)[(size_t)b*NUM_PROP + nsel] = mybox;
        nsel++;
        m &= ~shfl64(row, f);
      }
    }
    if (nsel >= NUM_PROP) break;
    for (uint32_t idx = r0 + (uint32_t)lane; idx < r1; idx += 64){
      uint32_t e = ebuf[idx];
      uint32_t il = e >> 16, j = e & 0xFFFFu;
      if (((sel >> il) & 1ull) && j >= (uint32_t)(base + 64))
        atomicOr(&suppr[j >> 5], 1u << (j & 31));
    }
  }
  for (uint32_t r = nsel + (uint32_t)lane; r < NUM_PROP; r += 64)
    ((float4*)out)[(size_t)b*NUM_PROP + r] = make_float4(0.f, 0.f, 0.f, 0.f);
}

extern "C" void kernel_launch(void* const* d_in, const int* in_sizes, int n_in,
                              void* d_out, int out_size, void* d_ws, size_t ws_size,
                              hipStream_t stream){
  const float* probs = (const float*)d_in[0];
  const float* boff  = (const float*)d_in[1];
  const float* anc   = (const float*)d_in[2];
  char* ws = (char*)d_ws;
  float* out = (float*)d_out;

  hipMemsetAsync(ws, 0, OFF_KEY, stream);  // zero state + both histograms
  k_hist1  <<<dim3(128, BATCH), 256, 0, stream>>>(probs, ws);
  k_resolve<<<BATCH, 256, 0, stream>>>(ws, 1);
  k_hist2  <<<dim3(128, BATCH), 256, 0, stream>>>(probs, ws);
  k_resolve<<<BATCH, 256, 0, stream>>>(ws, 2);
  k_compact<<<dim3(128, BATCH), 256, 0, stream>>>(probs, ws);
  k_rank   <<<dim3(CAND_CAP/256, BATCH), 256, 0, stream>>>(ws);
  k_gather <<<(BATCH*PRE_NMS + 255)/256, 256, 0, stream>>>(boff, anc, ws);
  k_edges  <<<dim3(NTILE*(NTILE+1)/2, BATCH), 64, 0, stream>>>(ws);
  k_scan   <<<BATCH, 256, 0, stream>>>(ws, out);
}